// Round 7
// baseline (1163.788 us; speedup 1.0000x reference)
//
#include <hip/hip_runtime.h>

#define N_OSC 50
#define N_PER 40
#define DT 0.01f
#define STEPS 100
#define BATCH 8192

// ws layout (float offsets)
#define WS_PC     0        // 50*240 packed consts
#define WS_DIRECT 12288    // 8192
#define WS_O0     20480    // 100*8192
#define WS_TORQ   839680   // 100*8192 reduced torque
#define WS_PART   1658880  // 50*100*8192 per-osc torque slices (163.84 MB)

// ---------------------------------------------------------------------------
// Prep: pack per-osc constants in contiguous-run layout (40-float runs):
//   pc[o*240 +   0.. 39] = e0[n]; [40..79] = e1[n]; [80..119] = d0[n]
//   [120..159] = d1[n];  [160..199] = w[n]; [200..239] = ob[n]
// ---------------------------------------------------------------------------
__global__ __launch_bounds__(256) void prep_kernel(
    const float* __restrict__ enc, const float* __restrict__ obias,
    const float* __restrict__ dec, const float* __restrict__ fc4_w,
    float* __restrict__ pc) {
    int idx = blockIdx.x * 256 + threadIdx.x;
    if (idx < N_OSC * N_PER) {
        int o = idx / N_PER, n = idx - o * N_PER;
        float* base = pc + o * 240;
        base[n]       = enc[o * 80 + 2 * n + 0];
        base[40 + n]  = enc[o * 80 + 2 * n + 1];
        base[80 + n]  = dec[o * 80 + n];
        base[120 + n] = dec[o * 80 + 40 + n];
        base[160 + n] = fc4_w[o * 40 + n];
        base[200 + n] = obias[o * 40 + n];
    }
}

// Zero torq (atomic-fallback mode only).
__global__ __launch_bounds__(256) void zero_kernel(float* __restrict__ torq) {
    int idx = blockIdx.x * 256 + threadIdx.x;
    ((float4*)torq)[idx] = make_float4(0.f, 0.f, 0.f, 0.f);
}

// ---------------------------------------------------------------------------
// MLP prologue. 1024 blocks x 256 threads, 8 batch rows per block.
// ---------------------------------------------------------------------------
__global__ __launch_bounds__(256) void mlp_kernel(
    const float* __restrict__ x,
    const float* __restrict__ fc1_w, const float* __restrict__ fc1_b,
    const float* __restrict__ fc2_w, const float* __restrict__ fc2_b,
    const float* __restrict__ fc3_w, const float* __restrict__ fc3_b,
    const float* __restrict__ fcd_w, const float* __restrict__ fcd_b,
    float* __restrict__ o0out, float* __restrict__ directout) {
    __shared__ float hs[8 * 132];
    __shared__ float h2s[8 * 132];
    int tid = threadIdx.x;
    int bb = tid & 7;
    int hw = tid >> 3;             // 0..31
    int b0 = blockIdx.x * 8;

    // fc1: h = relu(x @ fc1_w.T + b1), 8x128 outputs
    for (int idx = tid; idx < 8 * 128; idx += 256) {
        int r = idx >> 7, j = idx & 127;
        float x0 = x[(b0 + r) * 2], x1 = x[(b0 + r) * 2 + 1];
        float v = fmaf(x0, fc1_w[j * 2], fmaf(x1, fc1_w[j * 2 + 1], fc1_b[j]));
        hs[r * 132 + j] = fmaxf(v, 0.f);
    }
    __syncthreads();

    // direct = h . fcd_w + fcd_b
    if (tid < 8) {
        float s = fcd_b[0];
        #pragma unroll 8
        for (int k = 0; k < 128; k += 4) {
            float4 h4 = *(const float4*)&hs[tid * 132 + k];
            float4 w4 = *(const float4*)&fcd_w[k];
            s = fmaf(h4.x, w4.x, fmaf(h4.y, w4.y, fmaf(h4.z, w4.z, fmaf(h4.w, w4.w, s))));
        }
        directout[b0 + tid] = s;
    }

    // fc2: h2 = relu(h @ fc2_w.T + b2). Each thread: 4 j for its row.
    {
        int j0 = hw * 4;
        float a0 = fc2_b[j0], a1 = fc2_b[j0 + 1], a2 = fc2_b[j0 + 2], a3 = fc2_b[j0 + 3];
        const float* w0 = fc2_w + j0 * 128;
        const float* w1 = w0 + 128;
        const float* w2 = w0 + 256;
        const float* w3 = w0 + 384;
        #pragma unroll 8
        for (int k = 0; k < 128; k += 4) {
            float4 h4 = *(const float4*)&hs[bb * 132 + k];
            float4 q0 = *(const float4*)&w0[k];
            float4 q1 = *(const float4*)&w1[k];
            float4 q2 = *(const float4*)&w2[k];
            float4 q3 = *(const float4*)&w3[k];
            a0 = fmaf(h4.x, q0.x, fmaf(h4.y, q0.y, fmaf(h4.z, q0.z, fmaf(h4.w, q0.w, a0))));
            a1 = fmaf(h4.x, q1.x, fmaf(h4.y, q1.y, fmaf(h4.z, q1.z, fmaf(h4.w, q1.w, a1))));
            a2 = fmaf(h4.x, q2.x, fmaf(h4.y, q2.y, fmaf(h4.z, q2.z, fmaf(h4.w, q2.w, a2))));
            a3 = fmaf(h4.x, q3.x, fmaf(h4.y, q3.y, fmaf(h4.z, q3.z, fmaf(h4.w, q3.w, a3))));
        }
        h2s[bb * 132 + j0]     = fmaxf(a0, 0.f);
        h2s[bb * 132 + j0 + 1] = fmaxf(a1, 0.f);
        h2s[bb * 132 + j0 + 2] = fmaxf(a2, 0.f);
        h2s[bb * 132 + j0 + 3] = fmaxf(a3, 0.f);
    }
    __syncthreads();

    // fc3: x3 = h2 @ fc3_w.T + b3 (100 outputs) -> o0out[j][b]
    {
        int j0 = hw * 4;
        if (j0 < 100) {
            float a0 = fc3_b[j0], a1 = fc3_b[j0 + 1], a2 = fc3_b[j0 + 2], a3 = fc3_b[j0 + 3];
            const float* w0 = fc3_w + j0 * 128;
            const float* w1 = w0 + 128;
            const float* w2 = w0 + 256;
            const float* w3 = w0 + 384;
            #pragma unroll 8
            for (int k = 0; k < 128; k += 4) {
                float4 h4 = *(const float4*)&h2s[bb * 132 + k];
                float4 q0 = *(const float4*)&w0[k];
                float4 q1 = *(const float4*)&w1[k];
                float4 q2 = *(const float4*)&w2[k];
                float4 q3 = *(const float4*)&w3[k];
                a0 = fmaf(h4.x, q0.x, fmaf(h4.y, q0.y, fmaf(h4.z, q0.z, fmaf(h4.w, q0.w, a0))));
                a1 = fmaf(h4.x, q1.x, fmaf(h4.y, q1.y, fmaf(h4.z, q1.z, fmaf(h4.w, q1.w, a1))));
                a2 = fmaf(h4.x, q2.x, fmaf(h4.y, q2.y, fmaf(h4.z, q2.z, fmaf(h4.w, q2.w, a2))));
                a3 = fmaf(h4.x, q3.x, fmaf(h4.y, q3.y, fmaf(h4.z, q3.z, fmaf(h4.w, q3.w, a3))));
            }
            o0out[(j0)     * BATCH + b0 + bb] = a0;
            o0out[(j0 + 1) * BATCH + b0 + bb] = a1;
            o0out[(j0 + 2) * BATCH + b0 + bb] = a2;
            o0out[(j0 + 3) * BATCH + b0 + bb] = a3;
        }
    }
}

// ---------------------------------------------------------------------------
// Phase A (R7): SMEM-streamed constants -- no resident-constant file at all.
// R5/R6 post-mortem: the allocator parks any ~200-float pinned set in AGPRs
// (CDNA2-era cost model: AGPR file "free"; on gfx950 unified RF it is not)
// and pays ~200 v_accvgpr_read slots/step = the measured 228 us of issue vs
// 128 ideal. Pins and launch_bounds hints cannot override it -> stop keeping
// constants resident.
// Redesign: osc is derived ONLY from blockIdx (provably scalar -- unlike
// R1's wid-derived version that demanded an illegal v->s copy), so in-loop
// reads of pc[] are uniform loads: the backend emits s_load into SGPRs and
// folds each constant as the v_fma's single SGPR operand. The per-step
// "+s"(pcs) opaque forces re-streaming (K$/L2-hot, 48KB table) instead of
// hoisting 200 floats into registers. Only ob[40] lives in VGPRs (pinned) --
// the first fma of each n already consumes its SGPR slot with the e-coeff.
// ~60 VGPR demand -> no pressure -> no parking motive; 4+ waves/SIMD.
// Per-step issue: 245 VALU x 2cy + ~15 s_load slots ~= 520 cy vs 875 now.
// Store-mode (R5-proven): plain private-slice stores, zero sync, no atomics.
// Tripwires: VGPR_Count >= 200 => hoist happened; FETCH_SIZE at MB scale =>
// K$/L2 miss storm. Grid: 6400 blocks (50 osc x 128 bgroups) x 64 threads.
// ---------------------------------------------------------------------------
template<int MODE>
__global__ __launch_bounds__(64) void osc_kernel(const float* __restrict__ pc,
                                                 const float* __restrict__ o0init,
                                                 float* __restrict__ outbuf) {
    int lane = threadIdx.x;        // 0..63, one wave per block
    int blk = blockIdx.x;
    int osc = blk >> 7;            // 0..49  (scalar: blockIdx-derived only)
    int bg = blk & 127;            // batch group
    int b = bg * 64 + lane;

    const float* pco = pc + osc * 240;   // scalar address chain

    // obias -> VGPRs once, pinned (40 regs; each fma's SGPR slot carries the
    // e/d/w coefficient, so the addend must be a VGPR).
    float obv[40];
    #pragma unroll
    for (int n = 0; n < 40; ++n) obv[n] = pco[200 + n];
    #pragma unroll
    for (int n = 0; n < 40; ++n) asm volatile("" : "+v"(obv[n]));

    float s0 = o0init[(2 * osc) * BATCH + b];
    float s1 = o0init[(2 * osc + 1) * BATCH + b];

    // MODE 0: private slice base; MODE 1: shared torq base.
    float* outp = (MODE == 0) ? (outbuf + (size_t)osc * STEPS * BATCH + b)
                              : (outbuf + b);

    const float* pcs = pco;
    for (int step = 0; step < STEPS; ++step) {
        // Opaque the scalar base: constants must be re-streamed via s_load
        // each step (K$-hot) -- cannot be hoisted into a resident file.
        asm volatile("" : "+s"(pcs));
        float tq = 0.f, D0 = 0.f, D1 = 0.f;
        #pragma unroll
        for (int n = 0; n < 40; ++n) {
            float a = fmaf(s0, pcs[n], fmaf(s1, pcs[40 + n], obv[n]));
            a = fmaxf(a, 0.f);
            tq = fmaf(a, pcs[160 + n], tq);
            D0 = fmaf(a, pcs[80 + n],  D0);
            D1 = fmaf(a, pcs[120 + n], D1);
        }
        s0 = fmaf(DT, D0, s0);
        s1 = fmaf(DT, D1, s1);

        if (MODE == 0)
            outp[(size_t)step * BATCH] = tq;         // plain coalesced store
        else
            atomicAdd(&outp[(size_t)step * BATCH], tq);
    }
}

// ---------------------------------------------------------------------------
// Reduce: torq[step][b] = sum over 50 per-osc partials. Pure streaming:
// 164 MB read + 3.3 MB write, float4-vectorized, 800 blocks x 256 threads.
// ---------------------------------------------------------------------------
__global__ __launch_bounds__(256) void reduce_kernel(const float* __restrict__ part,
                                                     float* __restrict__ torq) {
    int i = blockIdx.x * 256 + threadIdx.x;          // float4 index, 204800 total
    const float4* p = (const float4*)part;
    float4 s0 = make_float4(0.f, 0.f, 0.f, 0.f);
    float4 s1 = make_float4(0.f, 0.f, 0.f, 0.f);
    #pragma unroll 5
    for (int o = 0; o < N_OSC; o += 2) {             // 2 accumulators for ILP
        float4 v0 = p[(size_t)o * 204800 + i];
        float4 v1 = p[(size_t)(o + 1) * 204800 + i];
        s0.x += v0.x; s0.y += v0.y; s0.z += v0.z; s0.w += v0.w;
        s1.x += v1.x; s1.y += v1.y; s1.z += v1.z; s1.w += v1.w;
    }
    ((float4*)torq)[i] = make_float4(s0.x + s1.x, s0.y + s1.y,
                                     s0.z + s1.z, s0.w + s1.w);
}

// ---------------------------------------------------------------------------
// Phase B: integrate pendulum; prefetch torq; packed float2 state store.
// ---------------------------------------------------------------------------
__global__ __launch_bounds__(256) void pend_kernel(const float* __restrict__ x,
                                                   const float* __restrict__ torq,
                                                   const float* __restrict__ direct,
                                                   const float* __restrict__ fc4_b,
                                                   float* __restrict__ out) {
    int b = blockIdx.x * 256 + threadIdx.x;
    float theta = x[2 * b];
    float omega = 0.f;
    float base = direct[b] + fc4_b[0];
    float2* out_l = (float2*)out;             // (100, 8192, 2)
    float* out_t = out + STEPS * BATCH * 2;   // (100, 8192)
    float pf[4];
    #pragma unroll
    for (int j = 0; j < 4; ++j) pf[j] = torq[j * BATCH + b];
    #pragma unroll 4
    for (int s = 0; s < STEPS; ++s) {
        float tq = base + pf[s & 3];
        if (s + 4 < STEPS) pf[s & 3] = torq[(s + 4) * BATCH + b];
        float alpha = tq - __sinf(theta) - 0.1f * omega;   // old theta, old omega
        theta = fmaf(DT, omega, theta);                    // uses old omega
        omega = fmaf(DT, alpha, omega);
        out_l[s * BATCH + b] = make_float2(theta, omega);
        out_t[s * BATCH + b] = tq;
    }
}

extern "C" void kernel_launch(void* const* d_in, const int* in_sizes, int n_in,
                              void* d_out, int out_size, void* d_ws, size_t ws_size,
                              hipStream_t stream) {
    const float* x     = (const float*)d_in[0];
    const float* fc1_w = (const float*)d_in[1];
    const float* fc1_b = (const float*)d_in[2];
    const float* fc2_w = (const float*)d_in[3];
    const float* fc2_b = (const float*)d_in[4];
    const float* fc3_w = (const float*)d_in[5];
    const float* fc3_b = (const float*)d_in[6];
    const float* fcd_w = (const float*)d_in[7];
    const float* fcd_b = (const float*)d_in[8];
    const float* enc   = (const float*)d_in[9];
    const float* obias = (const float*)d_in[10];
    const float* dec   = (const float*)d_in[11];
    const float* fc4_w = (const float*)d_in[12];
    const float* fc4_b = (const float*)d_in[13];
    float* out = (float*)d_out;
    float* ws = (float*)d_ws;

    float* pc      = ws + WS_PC;
    float* direct  = ws + WS_DIRECT;
    float* o0      = ws + WS_O0;
    float* torq    = ws + WS_TORQ;
    float* part    = ws + WS_PART;

    size_t need_bytes = ((size_t)WS_PART + (size_t)N_OSC * STEPS * BATCH) * sizeof(float);
    bool store_mode = ws_size >= need_bytes;

    hipLaunchKernelGGL(prep_kernel, dim3(8), dim3(256), 0, stream,
                       enc, obias, dec, fc4_w, pc);
    hipLaunchKernelGGL(mlp_kernel, dim3(BATCH / 8), dim3(256), 0, stream,
                       x, fc1_w, fc1_b, fc2_w, fc2_b, fc3_w, fc3_b,
                       fcd_w, fcd_b, o0, direct);
    if (store_mode) {
        hipLaunchKernelGGL(osc_kernel<0>, dim3(N_OSC * 128), dim3(64), 0, stream,
                           pc, o0, part);
        hipLaunchKernelGGL(reduce_kernel, dim3(STEPS * BATCH / 4 / 256), dim3(256),
                           0, stream, part, torq);
    } else {
        hipLaunchKernelGGL(zero_kernel, dim3(STEPS * BATCH / 4 / 256), dim3(256),
                           0, stream, torq);
        hipLaunchKernelGGL(osc_kernel<1>, dim3(N_OSC * 128), dim3(64), 0, stream,
                           pc, o0, torq);
    }
    hipLaunchKernelGGL(pend_kernel, dim3(BATCH / 256), dim3(256), 0, stream,
                       x, torq, direct, fc4_b, out);
}

// Round 8
// 455.785 us; speedup vs baseline: 2.5534x; 2.5534x over previous
//
#include <hip/hip_runtime.h>

#define N_OSC 50
#define N_PER 40
#define DT 0.01f
#define STEPS 100
#define BATCH 8192

// ws layout (float offsets)
#define WS_PC     0        // 50*240 packed consts
#define WS_DIRECT 12288    // 8192
#define WS_O0     20480    // 100*8192
#define WS_TORQ   839680   // 100*8192 reduced torque
#define WS_PART   1658880  // 50*100*8192 per-osc torque slices (163.84 MB)

// ---------------------------------------------------------------------------
// Prep: pack per-osc constants in contiguous-run layout (40-float runs):
//   pc[o*240 +   0.. 39] = e0[n]; [40..79] = e1[n]; [80..119] = d0[n]
//   [120..159] = d1[n];  [160..199] = w[n]; [200..239] = ob[n]
// ---------------------------------------------------------------------------
__global__ __launch_bounds__(256) void prep_kernel(
    const float* __restrict__ enc, const float* __restrict__ obias,
    const float* __restrict__ dec, const float* __restrict__ fc4_w,
    float* __restrict__ pc) {
    int idx = blockIdx.x * 256 + threadIdx.x;
    if (idx < N_OSC * N_PER) {
        int o = idx / N_PER, n = idx - o * N_PER;
        float* base = pc + o * 240;
        base[n]       = enc[o * 80 + 2 * n + 0];
        base[40 + n]  = enc[o * 80 + 2 * n + 1];
        base[80 + n]  = dec[o * 80 + n];
        base[120 + n] = dec[o * 80 + 40 + n];
        base[160 + n] = fc4_w[o * 40 + n];
        base[200 + n] = obias[o * 40 + n];
    }
}

// Zero torq (atomic-fallback mode only).
__global__ __launch_bounds__(256) void zero_kernel(float* __restrict__ torq) {
    int idx = blockIdx.x * 256 + threadIdx.x;
    ((float4*)torq)[idx] = make_float4(0.f, 0.f, 0.f, 0.f);
}

// ---------------------------------------------------------------------------
// MLP prologue. 1024 blocks x 256 threads, 8 batch rows per block.
// ---------------------------------------------------------------------------
__global__ __launch_bounds__(256) void mlp_kernel(
    const float* __restrict__ x,
    const float* __restrict__ fc1_w, const float* __restrict__ fc1_b,
    const float* __restrict__ fc2_w, const float* __restrict__ fc2_b,
    const float* __restrict__ fc3_w, const float* __restrict__ fc3_b,
    const float* __restrict__ fcd_w, const float* __restrict__ fcd_b,
    float* __restrict__ o0out, float* __restrict__ directout) {
    __shared__ float hs[8 * 132];
    __shared__ float h2s[8 * 132];
    int tid = threadIdx.x;
    int bb = tid & 7;
    int hw = tid >> 3;             // 0..31
    int b0 = blockIdx.x * 8;

    // fc1: h = relu(x @ fc1_w.T + b1), 8x128 outputs
    for (int idx = tid; idx < 8 * 128; idx += 256) {
        int r = idx >> 7, j = idx & 127;
        float x0 = x[(b0 + r) * 2], x1 = x[(b0 + r) * 2 + 1];
        float v = fmaf(x0, fc1_w[j * 2], fmaf(x1, fc1_w[j * 2 + 1], fc1_b[j]));
        hs[r * 132 + j] = fmaxf(v, 0.f);
    }
    __syncthreads();

    // direct = h . fcd_w + fcd_b
    if (tid < 8) {
        float s = fcd_b[0];
        #pragma unroll 8
        for (int k = 0; k < 128; k += 4) {
            float4 h4 = *(const float4*)&hs[tid * 132 + k];
            float4 w4 = *(const float4*)&fcd_w[k];
            s = fmaf(h4.x, w4.x, fmaf(h4.y, w4.y, fmaf(h4.z, w4.z, fmaf(h4.w, w4.w, s))));
        }
        directout[b0 + tid] = s;
    }

    // fc2: h2 = relu(h @ fc2_w.T + b2). Each thread: 4 j for its row.
    {
        int j0 = hw * 4;
        float a0 = fc2_b[j0], a1 = fc2_b[j0 + 1], a2 = fc2_b[j0 + 2], a3 = fc2_b[j0 + 3];
        const float* w0 = fc2_w + j0 * 128;
        const float* w1 = w0 + 128;
        const float* w2 = w0 + 256;
        const float* w3 = w0 + 384;
        #pragma unroll 8
        for (int k = 0; k < 128; k += 4) {
            float4 h4 = *(const float4*)&hs[bb * 132 + k];
            float4 q0 = *(const float4*)&w0[k];
            float4 q1 = *(const float4*)&w1[k];
            float4 q2 = *(const float4*)&w2[k];
            float4 q3 = *(const float4*)&w3[k];
            a0 = fmaf(h4.x, q0.x, fmaf(h4.y, q0.y, fmaf(h4.z, q0.z, fmaf(h4.w, q0.w, a0))));
            a1 = fmaf(h4.x, q1.x, fmaf(h4.y, q1.y, fmaf(h4.z, q1.z, fmaf(h4.w, q1.w, a1))));
            a2 = fmaf(h4.x, q2.x, fmaf(h4.y, q2.y, fmaf(h4.z, q2.z, fmaf(h4.w, q2.w, a2))));
            a3 = fmaf(h4.x, q3.x, fmaf(h4.y, q3.y, fmaf(h4.z, q3.z, fmaf(h4.w, q3.w, a3))));
        }
        h2s[bb * 132 + j0]     = fmaxf(a0, 0.f);
        h2s[bb * 132 + j0 + 1] = fmaxf(a1, 0.f);
        h2s[bb * 132 + j0 + 2] = fmaxf(a2, 0.f);
        h2s[bb * 132 + j0 + 3] = fmaxf(a3, 0.f);
    }
    __syncthreads();

    // fc3: x3 = h2 @ fc3_w.T + b3 (100 outputs) -> o0out[j][b]
    {
        int j0 = hw * 4;
        if (j0 < 100) {
            float a0 = fc3_b[j0], a1 = fc3_b[j0 + 1], a2 = fc3_b[j0 + 2], a3 = fc3_b[j0 + 3];
            const float* w0 = fc3_w + j0 * 128;
            const float* w1 = w0 + 128;
            const float* w2 = w0 + 256;
            const float* w3 = w0 + 384;
            #pragma unroll 8
            for (int k = 0; k < 128; k += 4) {
                float4 h4 = *(const float4*)&h2s[bb * 132 + k];
                float4 q0 = *(const float4*)&w0[k];
                float4 q1 = *(const float4*)&w1[k];
                float4 q2 = *(const float4*)&w2[k];
                float4 q3 = *(const float4*)&w3[k];
                a0 = fmaf(h4.x, q0.x, fmaf(h4.y, q0.y, fmaf(h4.z, q0.z, fmaf(h4.w, q0.w, a0))));
                a1 = fmaf(h4.x, q1.x, fmaf(h4.y, q1.y, fmaf(h4.z, q1.z, fmaf(h4.w, q1.w, a1))));
                a2 = fmaf(h4.x, q2.x, fmaf(h4.y, q2.y, fmaf(h4.z, q2.z, fmaf(h4.w, q2.w, a2))));
                a3 = fmaf(h4.x, q3.x, fmaf(h4.y, q3.y, fmaf(h4.z, q3.z, fmaf(h4.w, q3.w, a3))));
            }
            o0out[(j0)     * BATCH + b0 + bb] = a0;
            o0out[(j0 + 1) * BATCH + b0 + bb] = a1;
            o0out[(j0 + 2) * BATCH + b0 + bb] = a2;
            o0out[(j0 + 3) * BATCH + b0 + bb] = a3;
        }
    }
}

// ---------------------------------------------------------------------------
// Phase A (R8): R5's proven skeleton + 2 batch rows per lane.
// R7 post-mortem: SMEM streaming serialized on a 48-SGPR file (VALU 31%) --
// dead end. R5's measured issue = 880 cy/step-wave vs 480 useful: the ~400
// extra is per-WAVE constant-access overhead (RA parks ~200 consts in AGPRs,
// unified-file occupancy 1.5 w/SIMD, cross-file read per constant per step);
// R6 proved launch-bounds hints can't change the RA's choice.
// Fix: AMORTIZE. Each wave computes rows b and b+64 against the same
// constants, interleaved per-n so each constant is unparked ONCE and used
// twice (CSE). Per-wave-step: 2x480 useful + ~400 overhead = 680 cy/row
// (-23%); wave count halves to 3200 -> total VALU demand ~138 us.
// 8 independent dep chains/wave keep VALU fed at low occupancy.
// Store-mode (R5-proven): plain private-slice stores, zero sync, no atomics.
// Grid: 3200 blocks (50 osc x 64 bgroups of 128 rows) x 64 threads.
// ---------------------------------------------------------------------------
template<int MODE>
__global__ __launch_bounds__(64) void osc_kernel(const float* __restrict__ pc,
                                                 const float* __restrict__ o0init,
                                                 float* __restrict__ outbuf) {
    __shared__ float cs[240];
    int lane = threadIdx.x;        // 0..63, one wave per block
    int blk = blockIdx.x;
    int osc = blk >> 6;            // 0..49
    int bg = blk & 63;             // batch group of 128 rows
    int b = bg * 128 + lane;       // rows b and b+64

    if (lane < 60)
        ((float4*)cs)[lane] = ((const float4*)(pc + osc * 240))[lane];
    __syncthreads();

    // LDS -> VGPR-resident constants (200 floats), pinned so they stay put.
    float e0v[40], e1v[40], d0v[40], d1v[40], wv[40];
    #pragma unroll
    for (int n = 0; n < 40; ++n) {
        e0v[n] = cs[n];
        e1v[n] = cs[40 + n];
        d0v[n] = cs[80 + n];
        d1v[n] = cs[120 + n];
        wv[n]  = cs[160 + n];
    }
    #pragma unroll
    for (int n = 0; n < 40; ++n) {
        asm volatile("" : "+v"(e0v[n]));
        asm volatile("" : "+v"(e1v[n]));
        asm volatile("" : "+v"(d0v[n]));
        asm volatile("" : "+v"(d1v[n]));
        asm volatile("" : "+v"(wv[n]));
    }

    // obias -> SGPRs (wave-uniform); rides each fma's single scalar operand.
    float ob[40];
    #pragma unroll
    for (int n = 0; n < 40; ++n) {
        union { float f; int i; } u;
        u.f = cs[200 + n];
        u.i = __builtin_amdgcn_readfirstlane(u.i);
        ob[n] = u.f;
    }

    float sA0 = o0init[(2 * osc) * BATCH + b];
    float sA1 = o0init[(2 * osc + 1) * BATCH + b];
    float sB0 = o0init[(2 * osc) * BATCH + b + 64];
    float sB1 = o0init[(2 * osc + 1) * BATCH + b + 64];

    // MODE 0: private slice base; MODE 1: shared torq base.
    float* outp = (MODE == 0) ? (outbuf + (size_t)osc * STEPS * BATCH + b)
                              : (outbuf + b);

    for (int step = 0; step < STEPS; ++step) {
        float tqA = 0.f, D0A = 0.f, D1A = 0.f;
        float tqB = 0.f, D0B = 0.f, D1B = 0.f;
        #pragma unroll
        for (int n = 0; n < 40; ++n) {
            // Interleaved per-n: each constant unparked once, used twice.
            float aA = fmaf(sA0, e0v[n], fmaf(sA1, e1v[n], ob[n]));
            float aB = fmaf(sB0, e0v[n], fmaf(sB1, e1v[n], ob[n]));
            aA = fmaxf(aA, 0.f);
            aB = fmaxf(aB, 0.f);
            tqA = fmaf(aA, wv[n], tqA);
            tqB = fmaf(aB, wv[n], tqB);
            D0A = fmaf(aA, d0v[n], D0A);
            D0B = fmaf(aB, d0v[n], D0B);
            D1A = fmaf(aA, d1v[n], D1A);
            D1B = fmaf(aB, d1v[n], D1B);
        }
        sA0 = fmaf(DT, D0A, sA0);
        sA1 = fmaf(DT, D1A, sA1);
        sB0 = fmaf(DT, D0B, sB0);
        sB1 = fmaf(DT, D1B, sB1);

        if (MODE == 0) {
            outp[(size_t)step * BATCH]      = tqA;   // plain coalesced stores
            outp[(size_t)step * BATCH + 64] = tqB;
        } else {
            atomicAdd(&outp[(size_t)step * BATCH], tqA);
            atomicAdd(&outp[(size_t)step * BATCH + 64], tqB);
        }
    }
}

// ---------------------------------------------------------------------------
// Reduce: torq[step][b] = sum over 50 per-osc partials. Pure streaming:
// 164 MB read + 3.3 MB write, float4-vectorized, 800 blocks x 256 threads.
// ---------------------------------------------------------------------------
__global__ __launch_bounds__(256) void reduce_kernel(const float* __restrict__ part,
                                                     float* __restrict__ torq) {
    int i = blockIdx.x * 256 + threadIdx.x;          // float4 index, 204800 total
    const float4* p = (const float4*)part;
    float4 s0 = make_float4(0.f, 0.f, 0.f, 0.f);
    float4 s1 = make_float4(0.f, 0.f, 0.f, 0.f);
    #pragma unroll 5
    for (int o = 0; o < N_OSC; o += 2) {             // 2 accumulators for ILP
        float4 v0 = p[(size_t)o * 204800 + i];
        float4 v1 = p[(size_t)(o + 1) * 204800 + i];
        s0.x += v0.x; s0.y += v0.y; s0.z += v0.z; s0.w += v0.w;
        s1.x += v1.x; s1.y += v1.y; s1.z += v1.z; s1.w += v1.w;
    }
    ((float4*)torq)[i] = make_float4(s0.x + s1.x, s0.y + s1.y,
                                     s0.z + s1.z, s0.w + s1.w);
}

// ---------------------------------------------------------------------------
// Phase B: integrate pendulum; prefetch torq; packed float2 state store.
// ---------------------------------------------------------------------------
__global__ __launch_bounds__(256) void pend_kernel(const float* __restrict__ x,
                                                   const float* __restrict__ torq,
                                                   const float* __restrict__ direct,
                                                   const float* __restrict__ fc4_b,
                                                   float* __restrict__ out) {
    int b = blockIdx.x * 256 + threadIdx.x;
    float theta = x[2 * b];
    float omega = 0.f;
    float base = direct[b] + fc4_b[0];
    float2* out_l = (float2*)out;             // (100, 8192, 2)
    float* out_t = out + STEPS * BATCH * 2;   // (100, 8192)
    float pf[4];
    #pragma unroll
    for (int j = 0; j < 4; ++j) pf[j] = torq[j * BATCH + b];
    #pragma unroll 4
    for (int s = 0; s < STEPS; ++s) {
        float tq = base + pf[s & 3];
        if (s + 4 < STEPS) pf[s & 3] = torq[(s + 4) * BATCH + b];
        float alpha = tq - __sinf(theta) - 0.1f * omega;   // old theta, old omega
        theta = fmaf(DT, omega, theta);                    // uses old omega
        omega = fmaf(DT, alpha, omega);
        out_l[s * BATCH + b] = make_float2(theta, omega);
        out_t[s * BATCH + b] = tq;
    }
}

extern "C" void kernel_launch(void* const* d_in, const int* in_sizes, int n_in,
                              void* d_out, int out_size, void* d_ws, size_t ws_size,
                              hipStream_t stream) {
    const float* x     = (const float*)d_in[0];
    const float* fc1_w = (const float*)d_in[1];
    const float* fc1_b = (const float*)d_in[2];
    const float* fc2_w = (const float*)d_in[3];
    const float* fc2_b = (const float*)d_in[4];
    const float* fc3_w = (const float*)d_in[5];
    const float* fc3_b = (const float*)d_in[6];
    const float* fcd_w = (const float*)d_in[7];
    const float* fcd_b = (const float*)d_in[8];
    const float* enc   = (const float*)d_in[9];
    const float* obias = (const float*)d_in[10];
    const float* dec   = (const float*)d_in[11];
    const float* fc4_w = (const float*)d_in[12];
    const float* fc4_b = (const float*)d_in[13];
    float* out = (float*)d_out;
    float* ws = (float*)d_ws;

    float* pc      = ws + WS_PC;
    float* direct  = ws + WS_DIRECT;
    float* o0      = ws + WS_O0;
    float* torq    = ws + WS_TORQ;
    float* part    = ws + WS_PART;

    size_t need_bytes = ((size_t)WS_PART + (size_t)N_OSC * STEPS * BATCH) * sizeof(float);
    bool store_mode = ws_size >= need_bytes;

    hipLaunchKernelGGL(prep_kernel, dim3(8), dim3(256), 0, stream,
                       enc, obias, dec, fc4_w, pc);
    hipLaunchKernelGGL(mlp_kernel, dim3(BATCH / 8), dim3(256), 0, stream,
                       x, fc1_w, fc1_b, fc2_w, fc2_b, fc3_w, fc3_b,
                       fcd_w, fcd_b, o0, direct);
    if (store_mode) {
        hipLaunchKernelGGL(osc_kernel<0>, dim3(N_OSC * 64), dim3(64), 0, stream,
                           pc, o0, part);
        hipLaunchKernelGGL(reduce_kernel, dim3(STEPS * BATCH / 4 / 256), dim3(256),
                           0, stream, part, torq);
    } else {
        hipLaunchKernelGGL(zero_kernel, dim3(STEPS * BATCH / 4 / 256), dim3(256),
                           0, stream, torq);
        hipLaunchKernelGGL(osc_kernel<1>, dim3(N_OSC * 64), dim3(64), 0, stream,
                           pc, o0, torq);
    }
    hipLaunchKernelGGL(pend_kernel, dim3(BATCH / 256), dim3(256), 0, stream,
                       x, torq, direct, fc4_b, out);
}